// Round 10
// baseline (592.737 us; speedup 1.0000x reference)
//
#include <hip/hip_runtime.h>
#include <stdint.h>

// TBN BasicBlock on MI355X, round 10: r7 shell + zero-VALU tap addresses +
// 2-deep tap pipeline (tap t+1 ds_reads overlap tap t MFMAs), setprio.
//   out = x + conv3x3(sign(bn2(conv3x3(sign(bn1(x)), tern(w1)))), tern(w2))
// Conv: BM=512 px (16 rows) x BN=64 cout, 8 waves (512 thr), wave tile 64x64
// via mfma_i32_32x32x32_i8, K-loop = 4 ci-chunks of 64, A+B double-buffered
// (147584 B LDS, 1 block/CU, 2 waves/SIMD), chunk c+1 staged at top of chunk
// c (drained by the single per-chunk __syncthreads ~1000 cyc later).
// launch_bounds(512,1): ~177 live regs fit without spills at 2 waves/SIMD.

#define EPS 1e-5f

typedef int i32x4  __attribute__((ext_vector_type(4)));
typedef int i32x16 __attribute__((ext_vector_type(16)));

__device__ __forceinline__ void gload16(const void* g, void* l) {
  __builtin_amdgcn_global_load_lds(
      (const __attribute__((address_space(1))) void*)g,
      (__attribute__((address_space(3))) void*)l, 16, 0, 0);
}

// ---------------- stage 1: sum |w| for both weights (grid 72x2) -------------
__global__ __launch_bounds__(256) void wsum_kernel(const float* __restrict__ w1,
                                                   const float* __restrict__ w2,
                                                   float* __restrict__ partial) {
  __shared__ float red[256];
  const int t = threadIdx.x;
  const int b = blockIdx.x;
  const float* w = blockIdx.y ? w2 : w1;
  float s = 0.f;
#pragma unroll
  for (int i = 0; i < 32; ++i) s += fabsf(w[b * 256 + t + i * 18432]);
  red[t] = s;
  __syncthreads();
  for (int o = 128; o > 0; o >>= 1) {
    if (t < o) red[t] += red[t + o];
    __syncthreads();
  }
  if (t == 0) partial[(blockIdx.y << 7) + b] = red[0];
}

__global__ void delta_kernel(const float* __restrict__ p1, const float* __restrict__ p2,
                             float* __restrict__ delta) {
  const int t = threadIdx.x;
  if (t < 2) {
    const float* p = (t == 0) ? p1 : p2;
    double s = 0.0;
    for (int i = 0; i < 72; ++i) s += (double)p[i];
    delta[t] = 0.7f * (float)(s * (1.0 / 589824.0));
  }
}

// ------------- stage 2: quantize both weights (grid 2304x2) -----------------
// Global layout == conv LDS layout (staged linearly), r7 formula:
//   nb=co>>6, chunk=ci>>6, slot=(ci&63)>>4
//   off = nb*147456 + chunk*36864 + tap*4096 + slot*1024 + (co&63)*16 + (ci&15)
__global__ __launch_bounds__(256) void quant_kernel(const float* __restrict__ w1,
                                                    const float* __restrict__ w2,
                                                    const float* __restrict__ delta2,
                                                    int8_t* __restrict__ wq1,
                                                    int8_t* __restrict__ wq2,
                                                    float* __restrict__ psbase) {
  __shared__ float rs[256];
  __shared__ float rc[256];
  const int t = threadIdx.x;
  const int by = blockIdx.y;
  const float* w = by ? w2 : w1;
  int8_t* wq = by ? wq2 : wq1;
  const int idx = blockIdx.x * 256 + t;
  const float d = delta2[by];
  const float v = w[idx];
  const float av = fabsf(v);
  const bool m = av > d;
  const int co = idx / 2304;
  const int rem = idx - co * 2304;
  const int ci = rem / 9;
  const int tap = rem - ci * 9;
  wq[(co >> 6) * 147456 + (ci >> 6) * 36864 + tap * 4096 +
     (((ci & 63) >> 4) << 10) + ((co & 63) << 4) + (ci & 15)] =
      m ? (v > 0.f ? (int8_t)1 : (int8_t)-1) : (int8_t)0;
  rs[t] = m ? av : 0.f;
  rc[t] = m ? 1.f : 0.f;
  __syncthreads();
  for (int o = 128; o > 0; o >>= 1) {
    if (t < o) { rs[t] += rs[t + o]; rc[t] += rc[t + o]; }
    __syncthreads();
  }
  if (t == 0) { psbase[by * 4608 + blockIdx.x] = rs[0];
                psbase[by * 4608 + 2304 + blockIdx.x] = rc[0]; }
}

__global__ __launch_bounds__(256) void alpha_kernel(const float* __restrict__ ps1, const float* __restrict__ pc1,
                                                    const float* __restrict__ ps2, const float* __restrict__ pc2,
                                                    const float* __restrict__ g2, const float* __restrict__ b2,
                                                    const float* __restrict__ m2, const float* __restrict__ v2,
                                                    float* __restrict__ alphas,
                                                    float* __restrict__ inv2o, float* __restrict__ add2o) {
  __shared__ float rs[256];
  __shared__ float rc[256];
  const int t = threadIdx.x;
  float s1 = 0.f, c1 = 0.f, s2 = 0.f, c2 = 0.f;
#pragma unroll
  for (int i = 0; i < 9; ++i) {
    s1 += ps1[t + (i << 8)]; c1 += pc1[t + (i << 8)];
    s2 += ps2[t + (i << 8)]; c2 += pc2[t + (i << 8)];
  }
  rs[t] = s1; rc[t] = c1;
  __syncthreads();
  for (int o = 128; o > 0; o >>= 1) {
    if (t < o) { rs[t] += rs[t + o]; rc[t] += rc[t + o]; }
    __syncthreads();
  }
  if (t == 0) alphas[0] = rs[0] / fmaxf(rc[0], 1.f);
  __syncthreads();
  rs[t] = s2; rc[t] = c2;
  __syncthreads();
  for (int o = 128; o > 0; o >>= 1) {
    if (t < o) { rs[t] += rs[t + o]; rc[t] += rc[t + o]; }
    __syncthreads();
  }
  if (t == 0) alphas[1] = rs[0] / fmaxf(rc[0], 1.f);
  const float inv = g2[t] * rsqrtf(v2[t] + EPS);
  inv2o[t] = inv;
  add2o[t] = b2[t] - m2[t] * inv;
}

// -------- stage 3: bn1 + binarize + NCHW -> NHWC (+-1 int8) -----------------
__global__ __launch_bounds__(256) void bn_bin_kernel(const float* __restrict__ x,
                                                     const float* __restrict__ g1,
                                                     const float* __restrict__ b1,
                                                     const float* __restrict__ m1,
                                                     const float* __restrict__ v1,
                                                     int8_t* __restrict__ a1) {
  __shared__ int8_t lds[64 * 40];
  const int t = threadIdx.x;
  const int p0 = blockIdx.x << 6;
  const int c0 = blockIdx.y << 5;
  const int n = blockIdx.z;
  const int pl = t & 63;
  const int cl0 = t >> 6;
#pragma unroll
  for (int i = 0; i < 8; ++i) {
    const int cl = cl0 + (i << 2);
    const int c = c0 + cl;
    const float inv = g1[c] * rsqrtf(v1[c] + EPS);
    const float ad = b1[c] - m1[c] * inv;
    const float val = x[(((n << 8) + c) << 10) + p0 + pl];
    const float tt = fmaf(val, inv, ad);
    lds[pl * 40 + cl] = (tt >= 0.f) ? (int8_t)1 : (int8_t)-1;
  }
  __syncthreads();
  const int pl2 = t >> 2;
  const int s2 = (t & 3) << 3;
  const uint2 o = *(const uint2*)&lds[pl2 * 40 + s2];
  *(uint2*)&a1[(((n << 10) + p0 + pl2) << 8) + c0 + s2] = o;
}

// -------- stages 4/5: dbuf + pipelined implicit-GEMM conv3x3 (i8 MFMA) ------
struct Frag { i32x4 a00, a01, a10, a11, b00, b01, b10, b11; };  // aXY: mt,kh; bXY: nt,kh

#define LOADF(F, TAP, AR, BR) do {                                            \
  F.a00 = *(const i32x4*)((AR) + aOff0[TAP]);                                 \
  F.a01 = *(const i32x4*)((AR) + aOff0[TAP] + 18464);                         \
  F.a10 = *(const i32x4*)((AR) + aOff1[TAP]);                                 \
  F.a11 = *(const i32x4*)((AR) + aOff1[TAP] + 18464);                         \
  F.b00 = *(const i32x4*)((BR) + bOff + (TAP) * 4096);                        \
  F.b01 = *(const i32x4*)((BR) + bOff + (TAP) * 4096 + 2048);                 \
  F.b10 = *(const i32x4*)((BR) + bOff + (TAP) * 4096 + 512);                  \
  F.b11 = *(const i32x4*)((BR) + bOff + (TAP) * 4096 + 2048 + 512);           \
} while (0)

#define MMAF(F) do {                                                          \
  __builtin_amdgcn_s_setprio(1);                                              \
  acc00 = __builtin_amdgcn_mfma_i32_32x32x32_i8(F.a00, F.b00, acc00, 0, 0, 0);\
  acc01 = __builtin_amdgcn_mfma_i32_32x32x32_i8(F.a00, F.b10, acc01, 0, 0, 0);\
  acc10 = __builtin_amdgcn_mfma_i32_32x32x32_i8(F.a10, F.b00, acc10, 0, 0, 0);\
  acc11 = __builtin_amdgcn_mfma_i32_32x32x32_i8(F.a10, F.b10, acc11, 0, 0, 0);\
  acc00 = __builtin_amdgcn_mfma_i32_32x32x32_i8(F.a01, F.b01, acc00, 0, 0, 0);\
  acc01 = __builtin_amdgcn_mfma_i32_32x32x32_i8(F.a01, F.b11, acc01, 0, 0, 0);\
  acc10 = __builtin_amdgcn_mfma_i32_32x32x32_i8(F.a11, F.b01, acc10, 0, 0, 0);\
  acc11 = __builtin_amdgcn_mfma_i32_32x32x32_i8(F.a11, F.b11, acc11, 0, 0, 0);\
  __builtin_amdgcn_s_setprio(0);                                              \
} while (0)

#define STAGE(CH, AW, BW) do {                                                \
  const int8_t* wch = wnb + (CH) * 36864;                                     \
  const int cOff = (CH) << 6;                                                 \
  _Pragma("unroll")                                                           \
  for (int i = 0; i < 5; ++i) {                                               \
    if (i < 4 || tid < 256) {                                                 \
      gload16(act + srcA[i] + cOff, (AW) + dstA[i]);                          \
      const int idx = tid + (i << 9);                                         \
      gload16(wch + (idx << 4), (BW) + (idx << 4));                           \
    }                                                                         \
  }                                                                           \
} while (0)

#define CHUNK(CH, AR, BR, AW, BW, DOSTAGE) do {                               \
  if (DOSTAGE) STAGE((CH) + 1, AW, BW);                                       \
  Frag fa, fb;                                                                \
  LOADF(fa, 0, AR, BR); LOADF(fb, 1, AR, BR);                                 \
  MMAF(fa);                                                                   \
  LOADF(fa, 2, AR, BR); MMAF(fb);                                             \
  LOADF(fb, 3, AR, BR); MMAF(fa);                                             \
  LOADF(fa, 4, AR, BR); MMAF(fb);                                             \
  LOADF(fb, 5, AR, BR); MMAF(fa);                                             \
  LOADF(fa, 6, AR, BR); MMAF(fb);                                             \
  LOADF(fb, 7, AR, BR); MMAF(fa);                                             \
  LOADF(fa, 8, AR, BR); MMAF(fb);                                             \
  MMAF(fa);                                                                   \
} while (0)

template <int EPI>
__global__ __launch_bounds__(512, 1) void conv3x3_tbn(
    const int8_t* __restrict__ act,   // NHWC int8 [B*1024][256]
    const int8_t* __restrict__ wq,    // [nb4][chunk4][tap9][slot4][co64][16]
    const float* __restrict__ alphas, const int aidx,
    const float* __restrict__ inv2, const float* __restrict__ add2,  // EPI==0
    const float* __restrict__ xres,                                  // EPI==1
    int8_t* __restrict__ aout, float* __restrict__ fout) {
  __shared__ int8_t ldsA0[4 * 577 * 16];   // [slot4][px 576 + zero][16]; 36928
  __shared__ int8_t ldsA1[4 * 577 * 16];
  __shared__ int8_t ldsB0[9 * 4 * 64 * 16];  // [tap][slot4][co64][16]; 36864
  __shared__ int8_t ldsB1[9 * 4 * 64 * 16];

  const int tid = threadIdx.x;
  const int bid = blockIdx.x;
  const int L = (bid & 7) * 64 + (bid >> 3);  // XCD swizzle, 512 blocks
  const int mb = L >> 2;            // 128 pixel tiles (16 image rows each)
  const int nb = L & 3;             // cout quarter
  const int n = mb >> 1;
  const int y0 = (mb & 1) << 4;
  const int l = tid & 63;
  const int wid = tid >> 6;         // 8 waves, 2 image rows each
  const int lx = l & 31;
  const int lh = l >> 5;

  // ---- precomputed tap addresses (zero VALU in the tap loop) ----
  int aOff0[9], aOff1[9];
#pragma unroll
  for (int tap = 0; tap < 9; ++tap) {
    const int ky = tap / 3, kx = tap % 3;
    const int xs = lx + kx - 1;
    const bool xok = (unsigned)xs < 32u;
#pragma unroll
    for (int mt = 0; mt < 2; ++mt) {
      const int yr = (wid << 1) + mt + ky;               // A-tile row 0..17
      const bool ok = xok && ((unsigned)(y0 - 1 + yr) < 32u);
      const int apix = ok ? (yr << 5) + xs : 576;        // 576 = zero-px
      const int off = lh * 9232 + (apix << 4);
      if (mt == 0) aOff0[tap] = off; else aOff1[tap] = off;
    }
  }
  const int bOff = (lh << 10) + (lx << 4);

  // ---- A staging plan: 2304 granules = [slot 4][px 576], 16B each ----
  int srcA[5], dstA[5];
#pragma unroll
  for (int i = 0; i < 5; ++i) {
    const int idx = tid + (i << 9);
    const int sl = idx / 576;
    const int px = idx - sl * 576;
    int ys = y0 - 1 + (px >> 5);
    ys = ys < 0 ? 0 : (ys > 31 ? 31 : ys);  // clamp; OOB rows only via zero-px
    srcA[i] = (((n << 10) + (ys << 5) + (px & 31)) << 8) + (sl << 4);
    dstA[i] = sl * 9232 + (px << 4);
  }
  // zero-px (index 576) in both buffers, all 4 slots
  if (tid < 8) {
    int8_t* zb = (tid & 4) ? ldsA1 : ldsA0;
    *(i32x4*)(zb + (tid & 3) * 9232 + 9216) = (i32x4){0, 0, 0, 0};
  }

  i32x16 acc00 = (i32x16)(0), acc01 = (i32x16)(0);
  i32x16 acc10 = (i32x16)(0), acc11 = (i32x16)(0);

  const int8_t* wnb = wq + nb * 147456;

  STAGE(0, ldsA0, ldsB0);
  __syncthreads();

  CHUNK(0, ldsA0, ldsB0, ldsA1, ldsB1, true);  __syncthreads();
  CHUNK(1, ldsA1, ldsB1, ldsA0, ldsB0, true);  __syncthreads();
  CHUNK(2, ldsA0, ldsB0, ldsA1, ldsB1, true);  __syncthreads();
  CHUNK(3, ldsA1, ldsB1, ldsA0, ldsB0, false);

  // C/D (32x32): n(co) = lane&31, m(px) = (reg&3) + 8*(reg>>2) + 4*(lane>>5)
  const float alpha = alphas[aidx];
  if constexpr (EPI == 0) {
#define EPI0(ACC, MT, NT) {                                                  \
    const int co = (nb << 6) + ((NT) << 5) + lx;                             \
    const float inv = inv2[co];                                              \
    const float ad = add2[co];                                               \
    const int pixbase = (mb << 9) + (((wid << 1) + (MT)) << 5) + (lh << 2);  \
    _Pragma("unroll")                                                        \
    for (int rg = 0; rg < 16; ++rg) {                                        \
      const int pix = pixbase + (rg & 3) + ((rg >> 2) << 3);                 \
      const float h = alpha * (float)ACC[rg];                                \
      const float tt = fmaf(h, inv, ad);                                     \
      aout[(pix << 8) + co] = (tt >= 0.f) ? (int8_t)1 : (int8_t)-1;          \
    } }
    EPI0(acc00, 0, 0); EPI0(acc01, 0, 1); EPI0(acc10, 1, 0); EPI0(acc11, 1, 1);
  } else {
#define EPI1(ACC, MT, NT) {                                                  \
    const int co = (nb << 6) + ((NT) << 5) + lx;                             \
    const int pimg0 = ((mb & 1) << 9) + (((wid << 1) + (MT)) << 5) + (lh << 2); \
    _Pragma("unroll")                                                        \
    for (int qd = 0; qd < 4; ++qd) {                                         \
      const int off = (((n << 8) + co) << 10) + pimg0 + (qd << 3);           \
      const float4 xv = *(const float4*)(xres + off);                        \
      float4 o;                                                              \
      o.x = xv.x + alpha * (float)ACC[qd * 4 + 0];                           \
      o.y = xv.y + alpha * (float)ACC[qd * 4 + 1];                           \
      o.z = xv.z + alpha * (float)ACC[qd * 4 + 2];                           \
      o.w = xv.w + alpha * (float)ACC[qd * 4 + 3];                           \
      *(float4*)(fout + off) = o;                                            \
    } }
    EPI1(acc00, 0, 0); EPI1(acc01, 0, 1); EPI1(acc10, 1, 0); EPI1(acc11, 1, 1);
  }
}

extern "C" void kernel_launch(void* const* d_in, const int* in_sizes, int n_in,
                              void* d_out, int out_size, void* d_ws, size_t ws_size,
                              hipStream_t stream) {
  const float* x  = (const float*)d_in[0];
  const float* g1 = (const float*)d_in[1];
  const float* b1 = (const float*)d_in[2];
  const float* m1 = (const float*)d_in[3];
  const float* v1 = (const float*)d_in[4];
  const float* w1 = (const float*)d_in[5];
  const float* g2 = (const float*)d_in[6];
  const float* b2 = (const float*)d_in[7];
  const float* m2 = (const float*)d_in[8];
  const float* v2 = (const float*)d_in[9];
  const float* w2 = (const float*)d_in[10];
  float* out = (float*)d_out;

  char* ws = (char*)d_ws;
  int8_t* a1  = (int8_t*)(ws);                       // 16 MB
  int8_t* a2  = (int8_t*)(ws + 16777216);            // 16 MB
  int8_t* wq1 = (int8_t*)(ws + 33554432);            // 576 KB
  int8_t* wq2 = (int8_t*)(ws + 33554432 + 589824);   // 576 KB
  float* fs = (float*)(ws + 33554432 + 1179648);
  float* pd1    = fs;          // 72 entries
  float* pd2    = fs + 128;    // 72 entries
  float* deltas = fs + 256;
  float* alphas = fs + 260;
  float* psb    = fs + 512;    // ps1[2304], pc1[2304], ps2[2304], pc2[2304]
  float* inv2   = fs + 512 + 9216;
  float* add2   = fs + 512 + 9472;

  hipLaunchKernelGGL(wsum_kernel, dim3(72, 2), dim3(256), 0, stream, w1, w2, fs);
  hipLaunchKernelGGL(delta_kernel, dim3(1), dim3(64), 0, stream, pd1, pd2, deltas);
  hipLaunchKernelGGL(quant_kernel, dim3(2304, 2), dim3(256), 0, stream,
                     w1, w2, deltas, wq1, wq2, psb);
  hipLaunchKernelGGL(alpha_kernel, dim3(1), dim3(256), 0, stream,
                     psb, psb + 2304, psb + 4608, psb + 6912,
                     g2, b2, m2, v2, alphas, inv2, add2);
  hipLaunchKernelGGL(bn_bin_kernel, dim3(16, 8, 64), dim3(256), 0, stream, x, g1, b1, m1, v1, a1);
  hipLaunchKernelGGL((conv3x3_tbn<0>), dim3(512), dim3(512), 0, stream,
                     a1, wq1, alphas, 0, inv2, add2, (const float*)nullptr,
                     a2, (float*)nullptr);
  hipLaunchKernelGGL((conv3x3_tbn<1>), dim3(512), dim3(512), 0, stream,
                     a2, wq2, alphas, 1, (const float*)nullptr, (const float*)nullptr, x,
                     (int8_t*)nullptr, out);
  (void)in_sizes; (void)n_in; (void)out_size; (void)ws_size;
}

// Round 11
// 134.202 us; speedup vs baseline: 4.4167x; 4.4167x over previous
//
#include <hip/hip_runtime.h>
#include <stdint.h>

// TBN BasicBlock on MI355X, round 11: r6 conv verbatim with ONE change:
// __launch_bounds__(512,4) -> (512,2). Raises the per-wave register cap
// 64 -> ~128 arch (+64 acc) so the scheduler can hoist next-tap ds_reads
// over current-tap MFMAs inside the unrolled 9-tap block. LDS (73792 B)
// still pins occupancy at 2 blocks/CU, so this isolates register freedom.
//   out = x + conv3x3(sign(bn2(conv3x3(sign(bn1(x)), tern(w1)))), tern(w2))
// Conv: BM=512 px (16 rows) x BN=64 cout, 8 waves, wave tile 64x64 via
// mfma_i32_32x32x32_i8; K-loop = 4 ci-chunks of 64, all nine tap B-panels
// LDS-resident per chunk; 2 barriers/chunk.

#define EPS 1e-5f

typedef int i32x4  __attribute__((ext_vector_type(4)));
typedef int i32x16 __attribute__((ext_vector_type(16)));

__device__ __forceinline__ void gload16(const void* g, void* l) {
  __builtin_amdgcn_global_load_lds(
      (const __attribute__((address_space(1))) void*)g,
      (__attribute__((address_space(3))) void*)l, 16, 0, 0);
}

// ---------------- stage 1: sum |w| for both weights (grid 72x2) -------------
__global__ __launch_bounds__(256) void wsum_kernel(const float* __restrict__ w1,
                                                   const float* __restrict__ w2,
                                                   float* __restrict__ partial) {
  __shared__ float red[256];
  const int t = threadIdx.x;
  const int b = blockIdx.x;
  const float* w = blockIdx.y ? w2 : w1;
  float s = 0.f;
#pragma unroll
  for (int i = 0; i < 32; ++i) s += fabsf(w[b * 256 + t + i * 18432]);
  red[t] = s;
  __syncthreads();
  for (int o = 128; o > 0; o >>= 1) {
    if (t < o) red[t] += red[t + o];
    __syncthreads();
  }
  if (t == 0) partial[(blockIdx.y << 7) + b] = red[0];
}

__global__ void delta_kernel(const float* __restrict__ p1, const float* __restrict__ p2,
                             float* __restrict__ delta) {
  const int t = threadIdx.x;
  if (t < 2) {
    const float* p = (t == 0) ? p1 : p2;
    double s = 0.0;
    for (int i = 0; i < 72; ++i) s += (double)p[i];
    delta[t] = 0.7f * (float)(s * (1.0 / 589824.0));
  }
}

// ------------- stage 2: quantize both weights (grid 2304x2) -----------------
// Global layout == conv LDS layout (staged linearly):
//   nb=co>>6, chunk=ci>>6, slot=(ci&63)>>4
//   off = nb*147456 + chunk*36864 + tap*4096 + slot*1024 + (co&63)*16 + (ci&15)
__global__ __launch_bounds__(256) void quant_kernel(const float* __restrict__ w1,
                                                    const float* __restrict__ w2,
                                                    const float* __restrict__ delta2,
                                                    int8_t* __restrict__ wq1,
                                                    int8_t* __restrict__ wq2,
                                                    float* __restrict__ psbase) {
  __shared__ float rs[256];
  __shared__ float rc[256];
  const int t = threadIdx.x;
  const int by = blockIdx.y;
  const float* w = by ? w2 : w1;
  int8_t* wq = by ? wq2 : wq1;
  const int idx = blockIdx.x * 256 + t;
  const float d = delta2[by];
  const float v = w[idx];
  const float av = fabsf(v);
  const bool m = av > d;
  const int co = idx / 2304;
  const int rem = idx - co * 2304;
  const int ci = rem / 9;
  const int tap = rem - ci * 9;
  wq[(co >> 6) * 147456 + (ci >> 6) * 36864 + tap * 4096 +
     (((ci & 63) >> 4) << 10) + ((co & 63) << 4) + (ci & 15)] =
      m ? (v > 0.f ? (int8_t)1 : (int8_t)-1) : (int8_t)0;
  rs[t] = m ? av : 0.f;
  rc[t] = m ? 1.f : 0.f;
  __syncthreads();
  for (int o = 128; o > 0; o >>= 1) {
    if (t < o) { rs[t] += rs[t + o]; rc[t] += rc[t + o]; }
    __syncthreads();
  }
  if (t == 0) { psbase[by * 4608 + blockIdx.x] = rs[0];
                psbase[by * 4608 + 2304 + blockIdx.x] = rc[0]; }
}

__global__ __launch_bounds__(256) void alpha_kernel(const float* __restrict__ ps1, const float* __restrict__ pc1,
                                                    const float* __restrict__ ps2, const float* __restrict__ pc2,
                                                    const float* __restrict__ g2, const float* __restrict__ b2,
                                                    const float* __restrict__ m2, const float* __restrict__ v2,
                                                    float* __restrict__ alphas,
                                                    float* __restrict__ inv2o, float* __restrict__ add2o) {
  __shared__ float rs[256];
  __shared__ float rc[256];
  const int t = threadIdx.x;
  float s1 = 0.f, c1 = 0.f, s2 = 0.f, c2 = 0.f;
#pragma unroll
  for (int i = 0; i < 9; ++i) {
    s1 += ps1[t + (i << 8)]; c1 += pc1[t + (i << 8)];
    s2 += ps2[t + (i << 8)]; c2 += pc2[t + (i << 8)];
  }
  rs[t] = s1; rc[t] = c1;
  __syncthreads();
  for (int o = 128; o > 0; o >>= 1) {
    if (t < o) { rs[t] += rs[t + o]; rc[t] += rc[t + o]; }
    __syncthreads();
  }
  if (t == 0) alphas[0] = rs[0] / fmaxf(rc[0], 1.f);
  __syncthreads();
  rs[t] = s2; rc[t] = c2;
  __syncthreads();
  for (int o = 128; o > 0; o >>= 1) {
    if (t < o) { rs[t] += rs[t + o]; rc[t] += rc[t + o]; }
    __syncthreads();
  }
  if (t == 0) alphas[1] = rs[0] / fmaxf(rc[0], 1.f);
  const float inv = g2[t] * rsqrtf(v2[t] + EPS);
  inv2o[t] = inv;
  add2o[t] = b2[t] - m2[t] * inv;
}

// -------- stage 3: bn1 + binarize + NCHW -> NHWC (+-1 int8) -----------------
__global__ __launch_bounds__(256) void bn_bin_kernel(const float* __restrict__ x,
                                                     const float* __restrict__ g1,
                                                     const float* __restrict__ b1,
                                                     const float* __restrict__ m1,
                                                     const float* __restrict__ v1,
                                                     int8_t* __restrict__ a1) {
  __shared__ int8_t lds[64 * 40];
  const int t = threadIdx.x;
  const int p0 = blockIdx.x << 6;
  const int c0 = blockIdx.y << 5;
  const int n = blockIdx.z;
  const int pl = t & 63;
  const int cl0 = t >> 6;
#pragma unroll
  for (int i = 0; i < 8; ++i) {
    const int cl = cl0 + (i << 2);
    const int c = c0 + cl;
    const float inv = g1[c] * rsqrtf(v1[c] + EPS);
    const float ad = b1[c] - m1[c] * inv;
    const float val = x[(((n << 8) + c) << 10) + p0 + pl];
    const float tt = fmaf(val, inv, ad);
    lds[pl * 40 + cl] = (tt >= 0.f) ? (int8_t)1 : (int8_t)-1;
  }
  __syncthreads();
  const int pl2 = t >> 2;
  const int s2 = (t & 3) << 3;
  const uint2 o = *(const uint2*)&lds[pl2 * 40 + s2];
  *(uint2*)&a1[(((n << 10) + p0 + pl2) << 8) + c0 + s2] = o;
}

// -------- stages 4/5: per-chunk implicit-GEMM conv3x3 (i8 32x32 MFMA) -------
template <int EPI>
__global__ __launch_bounds__(512, 2) void conv3x3_tbn(
    const int8_t* __restrict__ act,   // NHWC int8 [B*1024][256]
    const int8_t* __restrict__ wq,    // [nb4][chunk4][tap9][slot4][co64][16]
    const float* __restrict__ alphas, const int aidx,
    const float* __restrict__ inv2, const float* __restrict__ add2,  // EPI==0
    const float* __restrict__ xres,                                  // EPI==1
    int8_t* __restrict__ aout, float* __restrict__ fout) {
  __shared__ int8_t ldsA[4 * 577 * 16];     // [slot][px 576 + zero][16B]; 36928 B
  __shared__ int8_t ldsB[9 * 4 * 64 * 16];  // [tap][slot][co 64][16B];   36864 B

  const int tid = threadIdx.x;
  const int bid = blockIdx.x;
  const int L = (bid & 7) * 64 + (bid >> 3);  // XCD swizzle, 512 blocks
  const int mb = L >> 2;            // 128 pixel tiles (16 image rows each)
  const int nb = L & 3;             // cout quarter (64 couts)
  const int n = mb >> 1;
  const int y0 = (mb & 1) << 4;
  const int l = tid & 63;
  const int wid = tid >> 6;         // 8 waves, 2 image rows each
  const int lx = l & 31;            // x position / co lane
  const int lh = l >> 5;            // k-half selector

  // ---- A staging: 2304 dest granules = [slot 4][px 576], 16B each ----
  int srcA[5];
#pragma unroll
  for (int i = 0; i < 5; ++i) {
    const int idx = tid + (i << 9);
    const int asl = idx / 576;
    const int apx = idx - asl * 576;
    int ys = y0 - 1 + (apx >> 5);
    ys = ys < 0 ? 0 : (ys > 31 ? 31 : ys);  // clamp (OOB rows only read via zero-px)
    srcA[i] = (((n << 10) + (ys << 5) + (apx & 31)) << 8) + (asl << 4);
  }
  if (tid < 4) *(i32x4*)(ldsA + tid * 9232 + 9216) = (i32x4){0, 0, 0, 0};

  i32x16 acc[2][2];
  acc[0][0] = (i32x16)(0); acc[0][1] = (i32x16)(0);
  acc[1][0] = (i32x16)(0); acc[1][1] = (i32x16)(0);

  const int8_t* wbase = wq + nb * 147456;

  // ---- prologue: stage chunk 0 ----
#pragma unroll
  for (int i = 0; i < 5; ++i) {
    const int idx = tid + (i << 9);
    if (i < 4 || tid < 256) {
      const int asl = idx / 576;
      const int apx = idx - asl * 576;
      gload16(act + srcA[i], ldsA + asl * 9232 + (apx << 4));
      gload16(wbase + (idx << 4), ldsB + (idx << 4));
    }
  }
  __syncthreads();  // implicit vmcnt(0): staged data visible

  for (int chunk = 0; chunk < 4; ++chunk) {
    __builtin_amdgcn_s_setprio(1);
    // ---- barrier-free 9-tap compute over resident chunk ----
#pragma unroll
    for (int tap = 0; tap < 9; ++tap) {
      const int ky = tap / 3, kx = tap % 3;
      const int xs = lx + kx - 1;
      const bool xok = (unsigned)xs < 32u;
      int apix[2];
#pragma unroll
      for (int mt = 0; mt < 2; ++mt) {
        const int yr = (wid << 1) + mt + ky;       // A-tile row 0..17
        const bool ok = xok && ((unsigned)(y0 - 1 + yr) < 32u);
        apix[mt] = ok ? (yr << 5) + xs : 576;      // zero-px for halo
      }
      i32x4 afr[2][2], bfr[2][2];
#pragma unroll
      for (int kh = 0; kh < 2; ++kh) {
        const int sl = lh + (kh << 1);
#pragma unroll
        for (int mt = 0; mt < 2; ++mt)
          afr[mt][kh] = *(const i32x4*)(ldsA + sl * 9232 + (apix[mt] << 4));
#pragma unroll
        for (int nt = 0; nt < 2; ++nt)
          bfr[nt][kh] = *(const i32x4*)(ldsB + (tap << 12) + (sl << 10) + ((nt << 5) + lx) * 16);
      }
#pragma unroll
      for (int mt = 0; mt < 2; ++mt)
#pragma unroll
        for (int nt = 0; nt < 2; ++nt)
#pragma unroll
          for (int kh = 0; kh < 2; ++kh)
            acc[mt][nt] = __builtin_amdgcn_mfma_i32_32x32x32_i8(afr[mt][kh], bfr[nt][kh], acc[mt][nt], 0, 0, 0);
    }
    __builtin_amdgcn_s_setprio(0);
    // ---- restage for next chunk ----
    if (chunk < 3) {
      __syncthreads();  // all waves done reading this chunk
      const int8_t* wch = wbase + (chunk + 1) * 36864;
#pragma unroll
      for (int i = 0; i < 5; ++i) {
        const int idx = tid + (i << 9);
        if (i < 4 || tid < 256) {
          const int asl = idx / 576;
          const int apx = idx - asl * 576;
          gload16(act + srcA[i] + ((chunk + 1) << 6), ldsA + asl * 9232 + (apx << 4));
          gload16(wch + (idx << 4), ldsB + (idx << 4));
        }
      }
      __syncthreads();  // drain
    }
  }

  // C/D (32x32): n(co) = lane&31, m(x) = (reg&3) + 8*(reg>>2) + 4*(lane>>5)
  const float alpha = alphas[aidx];
  if constexpr (EPI == 0) {
#pragma unroll
    for (int nt = 0; nt < 2; ++nt) {
      const int co = (nb << 6) + (nt << 5) + lx;
      const float inv = inv2[co];
      const float ad = add2[co];
#pragma unroll
      for (int mt = 0; mt < 2; ++mt) {
        const int pixbase = (mb << 9) + (((wid << 1) + mt) << 5) + (lh << 2);
#pragma unroll
        for (int rg = 0; rg < 16; ++rg) {
          const int pix = pixbase + (rg & 3) + ((rg >> 2) << 3);
          const float h = alpha * (float)acc[mt][nt][rg];
          const float tt = fmaf(h, inv, ad);
          aout[(pix << 8) + co] = (tt >= 0.f) ? (int8_t)1 : (int8_t)-1;
        }
      }
    }
  } else {
#pragma unroll
    for (int nt = 0; nt < 2; ++nt) {
      const int co = (nb << 6) + (nt << 5) + lx;
#pragma unroll
      for (int mt = 0; mt < 2; ++mt) {
        const int pimg0 = ((mb & 1) << 9) + (((wid << 1) + mt) << 5) + (lh << 2);
#pragma unroll
        for (int qd = 0; qd < 4; ++qd) {
          const int off = (((n << 8) + co) << 10) + pimg0 + (qd << 3);
          const float4 xv = *(const float4*)(xres + off);
          float4 o;
          o.x = xv.x + alpha * (float)acc[mt][nt][qd * 4 + 0];
          o.y = xv.y + alpha * (float)acc[mt][nt][qd * 4 + 1];
          o.z = xv.z + alpha * (float)acc[mt][nt][qd * 4 + 2];
          o.w = xv.w + alpha * (float)acc[mt][nt][qd * 4 + 3];
          *(float4*)(fout + off) = o;
        }
      }
    }
  }
}

extern "C" void kernel_launch(void* const* d_in, const int* in_sizes, int n_in,
                              void* d_out, int out_size, void* d_ws, size_t ws_size,
                              hipStream_t stream) {
  const float* x  = (const float*)d_in[0];
  const float* g1 = (const float*)d_in[1];
  const float* b1 = (const float*)d_in[2];
  const float* m1 = (const float*)d_in[3];
  const float* v1 = (const float*)d_in[4];
  const float* w1 = (const float*)d_in[5];
  const float* g2 = (const float*)d_in[6];
  const float* b2 = (const float*)d_in[7];
  const float* m2 = (const float*)d_in[8];
  const float* v2 = (const float*)d_in[9];
  const float* w2 = (const float*)d_in[10];
  float* out = (float*)d_out;

  char* ws = (char*)d_ws;
  int8_t* a1  = (int8_t*)(ws);                       // 16 MB
  int8_t* a2  = (int8_t*)(ws + 16777216);            // 16 MB
  int8_t* wq1 = (int8_t*)(ws + 33554432);            // 576 KB
  int8_t* wq2 = (int8_t*)(ws + 33554432 + 589824);   // 576 KB
  float* fs = (float*)(ws + 33554432 + 1179648);
  float* pd1    = fs;          // 72 entries
  float* pd2    = fs + 128;    // 72 entries
  float* deltas = fs + 256;
  float* alphas = fs + 260;
  float* psb    = fs + 512;    // ps1[2304], pc1[2304], ps2[2304], pc2[2304]
  float* inv2   = fs + 512 + 9216;
  float* add2   = fs + 512 + 9472;

  hipLaunchKernelGGL(wsum_kernel, dim3(72, 2), dim3(256), 0, stream, w1, w2, fs);
  hipLaunchKernelGGL(delta_kernel, dim3(1), dim3(64), 0, stream, pd1, pd2, deltas);
  hipLaunchKernelGGL(quant_kernel, dim3(2304, 2), dim3(256), 0, stream,
                     w1, w2, deltas, wq1, wq2, psb);
  hipLaunchKernelGGL(alpha_kernel, dim3(1), dim3(256), 0, stream,
                     psb, psb + 2304, psb + 4608, psb + 6912,
                     g2, b2, m2, v2, alphas, inv2, add2);
  hipLaunchKernelGGL(bn_bin_kernel, dim3(16, 8, 64), dim3(256), 0, stream, x, g1, b1, m1, v1, a1);
  hipLaunchKernelGGL((conv3x3_tbn<0>), dim3(512), dim3(512), 0, stream,
                     a1, wq1, alphas, 0, inv2, add2, (const float*)nullptr,
                     a2, (float*)nullptr);
  hipLaunchKernelGGL((conv3x3_tbn<1>), dim3(512), dim3(512), 0, stream,
                     a2, wq2, alphas, 1, (const float*)nullptr, (const float*)nullptr, x,
                     (int8_t*)nullptr, out);
  (void)in_sizes; (void)n_in; (void)out_size; (void)ws_size;
}